// Round 8
// baseline (109.623 us; speedup 1.0000x reference)
//
#include <hip/hip_runtime.h>

typedef __bf16 bf16;
typedef __attribute__((ext_vector_type(8))) bf16 bf16x8;
typedef __attribute__((ext_vector_type(4))) float f32x4;

namespace {

constexpr int NITERS = 50;   // R11 ERRATUM: ref's 50-iter iterate is NOT the
                             // fixed point; count must match exactly.
constexpr int KEXACT = 16;   // updates 0..15 use exact v_rcp (trans pipe);
                             // 16..49 use one Newton step.

// ---- compile-time physical constants (double) ----
constexpr double csqrt(double x) {
  double s = x > 1 ? x : 1;
  for (int i = 0; i < 60; ++i) s = 0.5 * (s + x / s);
  return s;
}
constexpr double AP_D =
    ((3.667 - 1.0) / (3.667 + 0.5)) * (0.3 * (7.5 * csqrt(7.5)) / 0.0002395);
constexpr double RGAST_D = (8.3144598 / 4184.0) * 623.15;

__device__ __forceinline__ float sss_val(int i, int j) {
  // SSS[i][j] = exp(-DELTAW/(RGAS*T)); symmetric; zero outside 51x51 (pad)
  if (i > 50 || j > 50) return 0.0f;
  const float si = -0.025f + 0.001f * (float)i;
  const float sj = -0.025f + 0.001f * (float)j;
  const float acc = fmaxf(0.0f, fmaxf(si, sj) - 0.0084f);
  const float don = fminf(0.0f, fminf(si, sj) + 0.0084f);
  const float dw = (float)(AP_D * 0.5) * (si + sj) * (si + sj) + 85580.0f * acc * don;
  return expf(-dw * (float)(1.0 / RGAST_D));
}

// Row-slot -> actual sigma-row. Slots 0..47 = rows 0..47. The 3 remaining
// real rows (48,49,50) live in tile-3 class r=0 (slots 48,52,56 = g 0..2);
// ALL of classes (tp=3, r>=1) are pad.
__device__ __forceinline__ int slot2row(int slot) {
  if (slot < 48) return slot;
  if ((slot & 3) == 0 && slot < 60) return 48 + ((slot - 48) >> 2);
  return 99;   // pad -> sss_val 0 / load 0
}

__device__ __forceinline__ float fast_log(float x) {
  return __builtin_amdgcn_logf(x) * 0.69314718056f;   // ln via log2
}

// HW-verified gfx950 shape (guide §3; R4/R5/R8/R9 passed with it).
__device__ __forceinline__ f32x4 mfma(bf16x8 a, bf16x8 b, f32x4 c) {
  return __builtin_amdgcn_mfma_f32_16x16x32_bf16(a, b, c, 0, 0, 0);
}

// Packed f32->bf16 (RNE, same rounding as the cast).
__device__ __forceinline__ unsigned cvt_pk(float lo, float hi) {
  unsigned r;
  asm("v_cvt_pk_bf16_f32 %0, %1, %2" : "=v"(r) : "v"(lo), "v"(hi));
  return r;
}

union B8 { unsigned u[4]; bf16x8 v; };

} // namespace

// One wave = ONE chain of 16 solves (8 elements x {pure,mix}); grid B/32,
// 4 waves/SIMD. R8: FULL UNROLL of the 50-step loop. Every prior version
// carried `#pragma unroll 1`, which forbids the scheduler from overlapping
// iteration k's update tail with iteration k+1's cvt/MFMA head across the
// back-edge (the one structural lever never tested; R4's manual rotation —
// the only real win since R1 — crudely approximated it). ~3.5K instr body,
// fits I-cache. No arithmetic change.
__global__ __launch_bounds__(256, 4) void cosmo_mfma_r8(
    const float* __restrict__ my_sigma,   // [B,51]
    const float* __restrict__ v_comp,     // [B]
    const float* __restrict__ vt_sigma,   // [B,51,2]
    const float* __restrict__ v_vt,       // [B]
    float* __restrict__ out,              // [B]
    int B)
{
  const int lane = threadIdx.x & 63;
  const int wv   = threadIdx.x >> 6;
  const int s    = lane & 15;     // solve slot (C col / A-frag m pos)
  const int g    = lane >> 4;     // lane group 0..3
  const int task = s & 1;         // 0 = pure, 1 = mix
  const int e    = blockIdx.x * 32 + wv * 8 + (s >> 1);
  const bool ein = (e < B);
  const int  ec  = ein ? e : 0;

  // ---- prologue: rows owned by this lane (slot = 16t+4g+r) ----
  float A0, A1;
  float wh[13], Gt[13], rc[13];   // 12 live elements tiles 0-2, + 1 (tile3,r0)
  {
    float myv[13], vtv[13];
#pragma unroll
    for (int t = 0; t < 4; ++t)
#pragma unroll
      for (int r = 0; r < 4; ++r) {
        const int li = 4 * t + r;
        if (li >= 13) continue;                  // tile3 r>=1: dead
        const int n  = slot2row(16 * t + 4 * g + r);
        const bool nv = (n < 51) && ein;
        const int nc = (n < 51) ? n : 50;
        myv[li] = nv ? my_sigma[(size_t)ec * 51 + nc] : 0.0f;
        vtv[li] = nv ? vt_sigma[((size_t)ec * 51 + nc) * 2 + 1] : 0.0f;
      }
    float pA0 = 0.f, pA1 = 0.f;
#pragma unroll
    for (int i = 0; i < 13; ++i) { pA0 += myv[i]; pA1 += vtv[i]; }
    pA0 += __shfl_xor(pA0, 16, 64); pA0 += __shfl_xor(pA0, 32, 64);
    pA1 += __shfl_xor(pA1, 16, 64); pA1 += __shfl_xor(pA1, 32, 64);
    A0 = pA0; A1 = pA1;

    const float den  = task ? (0.235f * pA0 + 0.765f * pA1) : pA0;
    const float rden = __builtin_amdgcn_rcpf(den);
    const float rdh  = 0.5f * rden;
#pragma unroll
    for (int i = 0; i < 13; ++i) {
      const float num = task ? (0.235f * myv[i] + 0.765f * vtv[i]) : myv[i];
      Gt[i] = num * rden;    // Gt = w * G, init G = 1; 0 on pads
      wh[i] = num * rdh;     // 0.5 * psigma (damped-update coefficient)
      rc[i] = 1.0f;
    }
  }

  // ---- constant A fragments (k-permuted, row-remapped):
  //      afr[tp][kt][i] = S[row(16tp+s)][row(16*(2kt+(i>>2)) + 4g + (i&3))] ----
  bf16x8 afr[4][2];
#pragma unroll
  for (int tp = 0; tp < 4; ++tp)
#pragma unroll
    for (int kt = 0; kt < 2; ++kt) {
      bf16x8 v;
#pragma unroll
      for (int i = 0; i < 8; ++i) {
        const int kslot = 16 * (2 * kt + (i >> 2)) + 4 * g + (i & 3);
        v[i] = (bf16)sss_val(slot2row(16 * tp + s), slot2row(kslot));
      }
      afr[tp][kt] = v;
    }

  // tile-3 acc init: element 0 slot = 48+4g -> pad iff g==3 (+1 -> d=1).
  f32x4 pad3;
  pad3[0] = (g == 3) ? 1.0f : 0.0f;
  pad3[1] = pad3[2] = pad3[3] = 1.0f;

  f32x4 acc[4];

  // Gt (13 f32) -> 7 packed dwords = the two bf16x8 B-fragments; 8 MFMA.
  auto matvec = [&]() {
    B8 x0, x1;
    x0.u[0] = cvt_pk(Gt[0],  Gt[1]);
    x0.u[1] = cvt_pk(Gt[2],  Gt[3]);
    x0.u[2] = cvt_pk(Gt[4],  Gt[5]);
    x0.u[3] = cvt_pk(Gt[6],  Gt[7]);
    x1.u[0] = cvt_pk(Gt[8],  Gt[9]);
    x1.u[1] = cvt_pk(Gt[10], Gt[11]);
    x1.u[2] = cvt_pk(Gt[12], 0.0f);
    x1.u[3] = 0;
    const bf16x8 b0 = x0.v, b1 = x1.v;

    const f32x4 z = {};
#pragma unroll
    for (int tp = 0; tp < 3; ++tp) acc[tp] = mfma(afr[tp][0], b0, z);
    acc[3] = mfma(afr[3][0], b0, pad3);
#pragma unroll
    for (int tp = 0; tp < 4; ++tp) acc[tp] = mfma(afr[tp][1], b1, acc[tp]);
  };

  auto upd_rcp = [&]() {
#pragma unroll
    for (int tp = 0; tp < 3; ++tp)
#pragma unroll
      for (int r = 0; r < 4; ++r) {
        const int i = 4 * tp + r;
        const float rcv = __builtin_amdgcn_rcpf(acc[tp][r]);
        rc[i] = rcv;
        Gt[i] = __builtin_fmaf(wh[i], rcv, 0.5f * Gt[i]);
      }
    {
      const float rcv = __builtin_amdgcn_rcpf(acc[3][0]);
      rc[12] = rcv;
      Gt[12] = __builtin_fmaf(wh[12], rcv, 0.5f * Gt[12]);
    }
  };

  auto upd_newton = [&]() {
#pragma unroll
    for (int tp = 0; tp < 3; ++tp)
#pragma unroll
      for (int r = 0; r < 4; ++r) {
        const int i = 4 * tp + r;
        const float nr  = __builtin_fmaf(-acc[tp][r], rc[i], 2.0f);
        const float rcv = rc[i] * nr;
        rc[i] = rcv;
        Gt[i] = __builtin_fmaf(wh[i], rcv, 0.5f * Gt[i]);
      }
    {
      const float nr  = __builtin_fmaf(-acc[3][0], rc[12], 2.0f);
      const float rcv = rc[12] * nr;
      rc[12] = rcv;
      Gt[12] = __builtin_fmaf(wh[12], rcv, 0.5f * Gt[12]);
    }
  };

  // ---- pipeline: d_0 in the prologue; update k consumes d_k, next matvec
  //      computes d_{k+1}. FULLY UNROLLED (no back-edge scheduling wall). ----
  matvec();
#pragma unroll
  for (int it = 0; it < KEXACT; ++it) { upd_rcp(); matvec(); }
#pragma unroll
  for (int it = KEXACT; it < NITERS - 1; ++it) { upd_newton(); matvec(); }
  upd_newton();   // final update (d_49) — no further matvec

  // ---- epilogue: S_task = sum_n psigma_pure[n] * ln(G[n]), G = Gt/w ----
  const float rA0 = __builtin_amdgcn_rcpf(A0);
  float Sp = 0.f;
#pragma unroll
  for (int t = 0; t < 4; ++t)
#pragma unroll
    for (int r = 0; r < 4; ++r) {
      const int li = 4 * t + r;
      if (li >= 13) continue;
      const int n = slot2row(16 * t + 4 * g + r);
      if (n < 51) {
        const float p  = (ein ? my_sigma[(size_t)ec * 51 + n] : 0.0f) * rA0;
        // guard w==0 (exact-0 input): p==0 there, force ln arg -> 1
        // G = Gt/w = Gt * rcp(2*wh) = Gt * 0.5 * rcp(wh)
        const float gg = (wh[li] != 0.0f)
                           ? Gt[li] * (0.5f * __builtin_amdgcn_rcpf(wh[li])) : 1.0f;
        Sp += p * __builtin_amdgcn_logf(gg);
      }
    }
  Sp += __shfl_xor(Sp, 16, 64);
  Sp += __shfl_xor(Sp, 32, 64);
  const float St = Sp * 0.69314718056f;
  const float So = __shfl_xor(St, 1, 64);   // partner task's sum

  if (task == 0 && g == 0 && ein) {
    const float lng_resid = A0 * (1.0f / 7.5f) * (So - St);
    const float v0  = v_comp[e];
    const float v1v = v_vt[e];
    const float q0 = A0 * (1.0f / 79.53f), q1 = A1 * (1.0f / 79.53f);
    const float r0 = v0 * (1.0f / 66.69f), r1 = v1v * (1.0f / 66.69f);
    const float xq = 0.235f * q0 + 0.765f * q1;
    const float xr = 0.235f * r0 + 0.765f * r1;
    const float theta = 0.235f * q0 * __builtin_amdgcn_rcpf(xq);
    const float phi   = 0.235f * r0 * __builtin_amdgcn_rcpf(xr);
    const float l0 = 5.0f * (r0 - q0) - (r0 - 1.0f);
    const float l1 = 5.0f * (r1 - q1) - (r1 - 1.0f);
    const float xl = 0.235f * l0 + 0.765f * l1;
    const float lng_comb = fast_log(phi * (1.0f / 0.235f))
                         + 5.0f * q0 * fast_log(theta * __builtin_amdgcn_rcpf(phi))
                         + l0 - (phi * (1.0f / 0.235f)) * xl;
    out[e] = lng_resid + lng_comb;
  }
}

extern "C" void kernel_launch(void* const* d_in, const int* in_sizes, int n_in,
                              void* d_out, int out_size, void* d_ws, size_t ws_size,
                              hipStream_t stream) {
  const float* my  = (const float*)d_in[0];
  const float* vc  = (const float*)d_in[1];
  const float* vts = (const float*)d_in[2];
  const float* vvt = (const float*)d_in[3];
  float* out = (float*)d_out;
  const int B = in_sizes[1];                    // v_compound is [B]
  const int grid = (B + 31) / 32;               // 32 elements per 256-thread block
  cosmo_mfma_r8<<<grid, 256, 0, stream>>>(my, vc, vts, vvt, out, B);
}

// Round 9
// 108.466 us; speedup vs baseline: 1.0107x; 1.0107x over previous
//
#include <hip/hip_runtime.h>

typedef __bf16 bf16;
typedef __attribute__((ext_vector_type(8))) bf16 bf16x8;
typedef __attribute__((ext_vector_type(16))) float f32x16;

namespace {

constexpr int NITERS = 50;   // R11 ERRATUM: ref's 50-iter iterate is NOT the
                             // fixed point; count must match exactly.
constexpr int KEXACT = 16;   // updates 0..15 exact v_rcp; 16..49 Newton.

// ---- compile-time physical constants (double) ----
constexpr double csqrt(double x) {
  double s = x > 1 ? x : 1;
  for (int i = 0; i < 60; ++i) s = 0.5 * (s + x / s);
  return s;
}
constexpr double AP_D =
    ((3.667 - 1.0) / (3.667 + 0.5)) * (0.3 * (7.5 * csqrt(7.5)) / 0.0002395);
constexpr double RGAST_D = (8.3144598 / 4184.0) * 623.15;

__device__ __forceinline__ float sss_val(int i, int j) {
  // SSS[i][j] = exp(-DELTAW/(RGAS*T)); symmetric; zero outside 51x51 (pad)
  if (i > 50 || j > 50) return 0.0f;
  const float si = -0.025f + 0.001f * (float)i;
  const float sj = -0.025f + 0.001f * (float)j;
  const float acc = fmaxf(0.0f, fmaxf(si, sj) - 0.0084f);
  const float don = fminf(0.0f, fminf(si, sj) + 0.0084f);
  const float dw = (float)(AP_D * 0.5) * (si + sj) * (si + sj) + 85580.0f * acc * don;
  return expf(-dw * (float)(1.0 / RGAST_D));
}

__device__ __forceinline__ float fast_log(float x) {
  return __builtin_amdgcn_logf(x) * 0.69314718056f;   // ln via log2
}

// 32x32x16 bf16 MFMA (m119: 2495 TF = 99.8% of dense peak, vs 16x16x32's
// 2075-2176 = 83-87%). Same MAC count for 51x51 padded-64 -> -12..17% MFMA
// bill per solve. C/D layout (m74/m101 HW-verified): col=lane&31,
// row=(reg&3)+8*(reg>>2)+4*(lane>>5).
__device__ __forceinline__ f32x16 mfma32(bf16x8 a, bf16x8 b, f32x16 c) {
  return __builtin_amdgcn_mfma_f32_32x32x16_bf16(a, b, c, 0, 0, 0);
}

// Packed f32->bf16 (RNE, same rounding as the cast).
__device__ __forceinline__ unsigned cvt_pk(float lo, float hi) {
  unsigned r;
  asm("v_cvt_pk_bf16_f32 %0, %1, %2" : "=v"(r) : "v"(lo), "v"(hi));
  return r;
}

union B8 { unsigned u[4]; bf16x8 v; };

// Row-slot of C/D position (t,reg) for lane-half h. Identity slot->sigma-row
// map; slots 51..63 are pad.
__device__ __forceinline__ constexpr int slot_of(int t, int reg, int h) {
  return 32 * t + (reg & 3) + 8 * (reg >> 2) + 4 * h;
}

// Live C/D classes: t=0 all 16 regs; t=1 regs 0..10 (8..10 half-live:
// h=0 slots 48/49/50 real, h=1 slots 52/53/54 pad). t=1 regs 11..15 dead.
__device__ __forceinline__ constexpr bool live_class(int t, int reg) {
  return (t == 0) || (reg < 11);
}

} // namespace

// R9: one wave = 32 solves (16 elements x {pure,mix}) via 32x32x16 MFMA.
// 2 row-tiles x 4 K-chunks = 8 MFMA per matvec of 32 solves (vs 8 per 16
// with 16x16x32). k-permutation: B chunk c element j holds the lane's OWN
// Gt[t=c>>1][reg=j+8*(c&1)] (q maps B position -> the lane's C slots; the
// HW k-encoding cancels because A fragments use the same q). Pad rows
// (slot>=51): acc-init 1.0 -> d=1, wh=0, Gt stays 0, no NaN.
// Grid B/64, 2 waves/SIMD (throughput-invariant per R2; MFMA-bound per R8
// closure: 16x16 path measured at 99-101% of its shape's issue ceiling).
__global__ __launch_bounds__(256, 2) void cosmo_mfma_r9(
    const float* __restrict__ my_sigma,   // [B,51]
    const float* __restrict__ v_comp,     // [B]
    const float* __restrict__ vt_sigma,   // [B,51,2]
    const float* __restrict__ v_vt,       // [B]
    float* __restrict__ out,              // [B]
    int B)
{
  const int lane = threadIdx.x & 63;
  const int wv   = threadIdx.x >> 6;
  const int n    = lane & 31;     // C col = solve index within wave
  const int h    = lane >> 5;     // row/k half
  const int task = n & 1;         // 0 = pure, 1 = mix
  const int e    = blockIdx.x * 64 + wv * 16 + (n >> 1);
  const bool ein = (e < B);
  const int  ec  = ein ? e : 0;

  float Gt[2][16], wh[2][16], rc[2][16];
#pragma unroll
  for (int t = 0; t < 2; ++t)
#pragma unroll
    for (int r = 0; r < 16; ++r) { Gt[t][r] = 0.0f; wh[t][r] = 0.0f; rc[t][r] = 1.0f; }

  // ---- prologue: this lane owns rows slot_of(t,reg,h) for its col ----
  float A0, A1;
  {
    float myv[2][16], vtv[2][16];
    float pA0 = 0.f, pA1 = 0.f;
#pragma unroll
    for (int t = 0; t < 2; ++t)
#pragma unroll
      for (int r = 0; r < 16; ++r) {
        if (!live_class(t, r)) continue;
        const int slot = slot_of(t, r, h);
        const bool nv = (slot < 51) && ein;
        const int sc = (slot < 51) ? slot : 50;
        myv[t][r] = nv ? my_sigma[(size_t)ec * 51 + sc] : 0.0f;
        vtv[t][r] = nv ? vt_sigma[((size_t)ec * 51 + sc) * 2 + 1] : 0.0f;
        pA0 += myv[t][r]; pA1 += vtv[t][r];
      }
    // the 2 lanes (h=0,h=1) of this col hold disjoint row sets covering 0..50
    pA0 += __shfl_xor(pA0, 32, 64);
    pA1 += __shfl_xor(pA1, 32, 64);
    A0 = pA0; A1 = pA1;

    const float den  = task ? (0.235f * pA0 + 0.765f * pA1) : pA0;
    const float rden = __builtin_amdgcn_rcpf(den);
    const float rdh  = 0.5f * rden;
#pragma unroll
    for (int t = 0; t < 2; ++t)
#pragma unroll
      for (int r = 0; r < 16; ++r) {
        if (!live_class(t, r)) continue;
        const float num = task ? (0.235f * myv[t][r] + 0.765f * vtv[t][r]) : myv[t][r];
        Gt[t][r] = num * rden;    // Gt = w * G, init G = 1; 0 on pads
        wh[t][r] = num * rdh;     // 0.5 * psigma
      }
  }

  // ---- constant A fragments: afr[t][c][j] = S[32t + n][q(c,h,j)] where
  //      q(c,h,j) = 32*(c>>1) + 16*(c&1) + 8*(j>>2) + (j&3) + 4h  ----
  bf16x8 afr[2][4];
#pragma unroll
  for (int t = 0; t < 2; ++t)
#pragma unroll
    for (int c = 0; c < 4; ++c) {
      bf16x8 v;
#pragma unroll
      for (int j = 0; j < 8; ++j) {
        const int kslot = 32 * (c >> 1) + 16 * (c & 1) + 8 * (j >> 2) + (j & 3) + 4 * h;
        v[j] = (bf16)sss_val(32 * t + n, kslot);
      }
      afr[t][c] = v;
    }

  // pad C-positions (slot>=51) init to 1.0 each matvec -> d=1 there.
  f32x16 pinit[2];
#pragma unroll
  for (int t = 0; t < 2; ++t)
#pragma unroll
    for (int r = 0; r < 16; ++r)
      pinit[t][r] = (slot_of(t, r, h) >= 51) ? 1.0f : 0.0f;

  f32x16 acc[2];

  // Gt -> 4 B-chunks (16 cvt_pk); 8 MFMA, two independent 4-deep acc chains.
  auto matvec = [&]() {
    B8 b[4];
#pragma unroll
    for (int c = 0; c < 4; ++c) {
      const int t = c >> 1, rb = 8 * (c & 1);
      b[c].u[0] = cvt_pk(Gt[t][rb + 0], Gt[t][rb + 1]);
      b[c].u[1] = cvt_pk(Gt[t][rb + 2], Gt[t][rb + 3]);
      b[c].u[2] = cvt_pk(Gt[t][rb + 4], Gt[t][rb + 5]);
      b[c].u[3] = cvt_pk(Gt[t][rb + 6], Gt[t][rb + 7]);
    }
    acc[0] = mfma32(afr[0][0], b[0].v, pinit[0]);
    acc[1] = mfma32(afr[1][0], b[0].v, pinit[1]);
#pragma unroll
    for (int c = 1; c < 4; ++c) {
      acc[0] = mfma32(afr[0][c], b[c].v, acc[0]);
      acc[1] = mfma32(afr[1][c], b[c].v, acc[1]);
    }
  };

  auto upd_rcp = [&]() {
#pragma unroll
    for (int t = 0; t < 2; ++t)
#pragma unroll
      for (int r = 0; r < 16; ++r) {
        if (!live_class(t, r)) continue;
        const float rcv = __builtin_amdgcn_rcpf(acc[t][r]);
        rc[t][r] = rcv;
        Gt[t][r] = __builtin_fmaf(wh[t][r], rcv, 0.5f * Gt[t][r]);
      }
  };

  auto upd_newton = [&]() {
#pragma unroll
    for (int t = 0; t < 2; ++t)
#pragma unroll
      for (int r = 0; r < 16; ++r) {
        if (!live_class(t, r)) continue;
        const float nr  = __builtin_fmaf(-acc[t][r], rc[t][r], 2.0f);
        const float rcv = rc[t][r] * nr;
        rc[t][r] = rcv;
        Gt[t][r] = __builtin_fmaf(wh[t][r], rcv, 0.5f * Gt[t][r]);
      }
  };

  // ---- rotated pipeline: d_0 in prologue; update k consumes d_k ----
  matvec();
#pragma unroll 1
  for (int it = 0; it < KEXACT; ++it) { upd_rcp(); matvec(); }
#pragma unroll 1
  for (int it = KEXACT; it < NITERS - 1; ++it) { upd_newton(); matvec(); }
  upd_newton();   // final update (d_49)

  // ---- epilogue: S_task = sum_n psigma_pure[n] * ln(G[n]), G = Gt/w ----
  const float rA0 = __builtin_amdgcn_rcpf(A0);
  float Sp = 0.f;
#pragma unroll
  for (int t = 0; t < 2; ++t)
#pragma unroll
    for (int r = 0; r < 16; ++r) {
      if (!live_class(t, r)) continue;
      const int slot = slot_of(t, r, h);
      const bool nv = (slot < 51) && ein;
      const int sc = (slot < 51) ? slot : 50;
      const float p  = (nv ? my_sigma[(size_t)ec * 51 + sc] : 0.0f) * rA0;
      // guard w==0 (pad or exact-0 input): p==0 there, force ln arg -> 1
      const float gg = (wh[t][r] != 0.0f)
                         ? Gt[t][r] * (0.5f * __builtin_amdgcn_rcpf(wh[t][r])) : 1.0f;
      Sp += p * __builtin_amdgcn_logf(gg);
    }
  Sp += __shfl_xor(Sp, 32, 64);             // combine the two row-halves
  const float St = Sp * 0.69314718056f;
  const float So = __shfl_xor(St, 1, 64);   // partner task's sum (col n^1)

  if (task == 0 && h == 0 && ein) {
    const float lng_resid = A0 * (1.0f / 7.5f) * (So - St);
    const float v0  = v_comp[e];
    const float v1v = v_vt[e];
    const float q0 = A0 * (1.0f / 79.53f), q1 = A1 * (1.0f / 79.53f);
    const float r0 = v0 * (1.0f / 66.69f), r1 = v1v * (1.0f / 66.69f);
    const float xq = 0.235f * q0 + 0.765f * q1;
    const float xr = 0.235f * r0 + 0.765f * r1;
    const float theta = 0.235f * q0 * __builtin_amdgcn_rcpf(xq);
    const float phi   = 0.235f * r0 * __builtin_amdgcn_rcpf(xr);
    const float l0 = 5.0f * (r0 - q0) - (r0 - 1.0f);
    const float l1 = 5.0f * (r1 - q1) - (r1 - 1.0f);
    const float xl = 0.235f * l0 + 0.765f * l1;
    const float lng_comb = fast_log(phi * (1.0f / 0.235f))
                         + 5.0f * q0 * fast_log(theta * __builtin_amdgcn_rcpf(phi))
                         + l0 - (phi * (1.0f / 0.235f)) * xl;
    out[e] = lng_resid + lng_comb;
  }
}

extern "C" void kernel_launch(void* const* d_in, const int* in_sizes, int n_in,
                              void* d_out, int out_size, void* d_ws, size_t ws_size,
                              hipStream_t stream) {
  const float* my  = (const float*)d_in[0];
  const float* vc  = (const float*)d_in[1];
  const float* vts = (const float*)d_in[2];
  const float* vvt = (const float*)d_in[3];
  float* out = (float*)d_out;
  const int B = in_sizes[1];                    // v_compound is [B]
  const int grid = (B + 63) / 64;               // 64 elements per 256-thread block
  cosmo_mfma_r9<<<grid, 256, 0, stream>>>(my, vc, vts, vvt, out, B);
}